// Round 5
// baseline (170.189 us; speedup 1.0000x reference)
//
#include <hip/hip_runtime.h>

#define HIMG 256
#define WIMG 256
#define CCH  32
#define JBOX 64
#define BIMG 8
#define HGT  8
#define MAXR 34    // rows per slab: ceil(bh)+2 <= 34 (bh < 32)

// R15: y-slab staging -- test the HBM read-pattern theory.
// Five schedules (R10-R14) all land at 54us with every CU pipe idle and
// combined HBM at 3.0 TB/s => the binder is the memory system's response
// to the ACCESS PATTERN, not the schedule. This version maximizes read
// sequentiality: one block = (box, channel), stages its full y-slab
// (<=34 full 1KB image rows = one dense 25-34KB sequential burst via
// global_load_lds) ONCE, then computes all 8 h from LDS.
// - 16 barriers/block -> 1; stage latency exposed once, hidden by 4
//   resident blocks/CU at unsynchronized phases.
// - XCD swizzle: b = g&7 (each XCD reads only its own 8MB image);
//   generation = 2 channels x 64 boxes => ~1.5MB, L2-resident.
// - Numerics identical to R14 (passed): same tap expressions, same
//   rounding, same blend grouping; slab index r = y0-ylo (clamps are
//   memory-safety guards only, never bind per box bounds).
typedef __attribute__((address_space(3))) float lds_f;
typedef const __attribute__((address_space(1))) float glb_f;

__global__ __launch_bounds__(192, 3) void roi_kernel(
    const float* __restrict__ img,     // (B, C, HIMG, WIMG)
    const float* __restrict__ boxes,   // (B, J, 5)
    float* __restrict__ res,           // (B, J, C, HGT, max_w)
    float* __restrict__ mask,          // (B, J, max_w)
    int max_w)
{
    __shared__ float srows[MAXR][WIMG];   // 34,816 B -> 4 blocks/CU

    const int g   = blockIdx.x;
    const int b   = g & 7;                 // XCD-pinned image
    const int idx = g >> 3;                // 0..2047
    const int c   = idx >> 6;              // channel 0..31
    const int j   = idx & 63;              // box within image
    const int bj  = b * JBOX + j;
    const int tid = threadIdx.x;

    const float left = boxes[bj * 5 + 0];
    const float top  = boxes[bj * 5 + 1];
    const float bw   = boxes[bj * 5 + 2] - left;
    const float bh   = boxes[bj * 5 + 3] - top;

    // width = int32(bw/bh * 8) with f32 ops + truncation (matches numpy).
    const int   width  = (int)(bw / bh * 8.0f);
    const float each_w = bw / ((float)width - 1.0f);
    const float each_h = bh / 7.0f;

    // slab bounds, derived with the SAME rounding as the consume taps so
    // r = y0 - ylo is exact: ylo = floor(y(0)), yhi = floor(y(7)) + 1.
    const int   ylo = min(max((int)floorf(top), 0), HIMG - 1);
    const float y7  = __fadd_rn(__fmul_rn(7.0f, each_h), top);
    const int   yhi = min(max((int)floorf(y7) + 1, 0), HIMG - 1);
    const int   nr  = min(yhi - ylo + 1, MAXR);   // <= 34

    // ---- stage: wave wv DMAs rows r = wv, wv+3, ... (full 1KB rows,
    //      perfectly sequential per row; rows ascending => dense burst) ----
    const int wv   = tid >> 6;             // 0..2, wave-uniform
    const int lane = tid & 63;
    const float* chbase = img + (size_t)(b * CCH + c) * (HIMG * WIMG);
    for (int r = wv; r < nr; r += 3) {     // uniform trip count per wave
        const float* src = chbase + (size_t)(ylo + r) * WIMG + 4 * lane;
        __builtin_amdgcn_global_load_lds((glb_f*)src, (lds_f*)&srows[r][0], 16, 0, 0);
    }
    __syncthreads();   // vmcnt(0)+barrier: all rows visible to the block

    const int  i = tid;
    if (i >= max_w) return;               // after the barrier: safe
    const bool in_w = (i < width);

    if (c == 0) {
        mask[(size_t)bj * max_w + i] = in_w ? 1.0f : 0.0f;
    }

    // per-thread x taps (h-invariant); separate roundings match numpy.
    const float x  = __fadd_rn(__fmul_rn((float)i, each_w), left);
    const int   xf = (int)floorf(x);
    const int   x0 = min(max(xf, 0), WIMG - 1);
    const float wx1 = (float)(x0 + 1) - x;
    const float wx0 = x - (float)x0;
    const int   lx  = min(x0, WIMG - 2);   // lx+1 <= 255, in-row

    float* resp = res + ((size_t)(bj * CCH + c) * HGT) * (size_t)max_w + i;

    #pragma unroll
    for (int h = 0; h < HGT; ++h) {
        // y taps (block-uniform; identical rounding to R14/staging).
        const float yh  = __fadd_rn(__fmul_rn((float)h, each_h), top);
        const int   yfl = (int)floorf(yh);
        const int   ya  = min(max(yfl,     0), HIMG - 1);
        const int   yb  = min(max(yfl + 1, 0), HIMG - 1);
        const float wy1 = (float)yb - yh;
        const float wy0 = yh - (float)ya;
        const int   r0  = min(max(ya - ylo, 0), MAXR - 1);  // guards only
        const int   r1  = min(max(yb - ylo, 0), MAXR - 1);

        const float wa  = wx1 * wy1;
        const float wb_ = wx1 * wy0;
        const float wc_ = wx0 * wy1;
        const float wd_ = wx0 * wy0;

        const float v00 = srows[r0][lx];       // ds_read2_b32 pair
        const float v01 = srows[r0][lx + 1];
        const float v10 = srows[r1][lx];       // ds_read2_b32 pair
        const float v11 = srows[r1][lx + 1];
        // identical term order/grouping to R11-R14 (passed absmax):
        const float val = v00 * wa + v10 * wb_ + v01 * wc_ + v11 * wd_;
        resp[(size_t)h * max_w] = in_w ? val : 0.0f;
    }
}

extern "C" void kernel_launch(void* const* d_in, const int* in_sizes, int n_in,
                              void* d_out, int out_size, void* d_ws, size_t ws_size,
                              hipStream_t stream) {
    const float* img   = (const float*)d_in[0];
    const float* boxes = (const float*)d_in[1];
    float* out = (float*)d_out;

    const int per_w = BIMG * JBOX * CCH * HGT + BIMG * JBOX;  // 131584
    const int max_w = out_size / per_w;

    float* res  = out;
    float* mask = out + (size_t)BIMG * JBOX * CCH * HGT * max_w;

    const int blocks = BIMG * JBOX * CCH;   // 16384 = (box, channel)
    roi_kernel<<<blocks, 192, 0, stream>>>(img, boxes, res, mask, max_w);
}

// Round 6
// 166.984 us; speedup vs baseline: 1.0192x; 1.0192x over previous
//
#include <hip/hip_runtime.h>

#define HIMG 256
#define WIMG 256
#define CCH  32
#define JBOX 64
#define BIMG 8
#define HGT  8
#define CPB  8     // channels per block
#define NCG  (CCH / CPB)   // 4

// R16: NO LDS, NO barriers, NO DMA -- direct per-lane gather through L1/L2.
// Evidence chain: R11 (conflict-free LDS) null; R12/R13 (reg prefetch,
// collapsed) null; R14 (real DMA pipeline, full occupancy) null; R15
// (slab staging) proved reads are L2/L3-resident (FETCH 76->28 MB) yet
// got slower. The shared constant of all variants was the LDS+barrier
// convoy quantizing each wave's progress to one tiny tile per memory
// round-trip (delivered 8 B/cy/CU with ~64KB/CU in flight => ~10Kcy
// effective latency = queueing by convoy). This is Common-mistake #7:
// staging cache-fit data. R16 removes the machinery entirely:
// - thread = output col i of (bj, cg); loops 8 ch x 8 h; 4 clamped
//   dword gathers per (c,h). Wave tap span ~1KB -> TA coalesces, L1/L2
//   serve with heavy intra-wave line reuse (each_w <= 4).
// - zero barriers: waves independent, compiler pipelines loads across
//   the unrolled c/h loops, 32 waves/CU TLP hides latency.
// - nontemporal output stores (eviction hint, coherent via L2): keeps
//   L2 capacity for the image.
// - numerics: tap selection / rounding / blend grouping byte-identical
//   to R11-R15 (all passed absmax 0.0156).
__global__ __launch_bounds__(256, 8) void roi_kernel(
    const float* __restrict__ img,     // (B, C, HIMG, WIMG)
    const float* __restrict__ boxes,   // (B, J, 5)
    float* __restrict__ res,           // (B, J, C, HGT, max_w)
    float* __restrict__ mask,          // (B, J, max_w)
    int max_w)
{
    const int d    = blockIdx.x;
    const int slot = d & 7;                   // XCD; each XCD reads 1 image
    const int seq  = d >> 3;                  // 0..255
    const int bj   = slot * ((BIMG * JBOX) / 8) + (seq >> 2);
    const int cg   = seq & 3;                 // channel group (8 ch)
    const int b    = bj >> 6;                 // J = 64
    const int tid  = threadIdx.x;

    const float left = boxes[bj * 5 + 0];
    const float top  = boxes[bj * 5 + 1];
    const float bw   = boxes[bj * 5 + 2] - left;
    const float bh   = boxes[bj * 5 + 3] - top;

    // width = int32(bw/bh * 8) with f32 ops + truncation (matches numpy).
    const int   width  = (int)(bw / bh * 8.0f);
    const float each_w = bw / ((float)width - 1.0f);
    const float each_h = bh / 7.0f;

    const int  i = tid;
    if (i >= max_w) return;                   // no barriers below: safe
    const bool in_w = (i < width);

    if (cg == 0) {
        mask[(size_t)bj * max_w + i] = in_w ? 1.0f : 0.0f;
    }

    // per-thread x taps (h-invariant); separate roundings match numpy.
    const float x  = __fadd_rn(__fmul_rn((float)i, each_w), left);
    const int   xf = (int)floorf(x);
    const int   x0 = min(max(xf, 0), WIMG - 1);
    const float wx1 = (float)(x0 + 1) - x;
    const float wx0 = x - (float)x0;
    const int   lx  = min(x0, WIMG - 2);      // lx+1 in-row; never binds in-width

    const float* base = img + ((size_t)b * CCH + cg * CPB) * (HIMG * WIMG) + lx;
    float* resp0 = res + (((size_t)bj * CCH + cg * CPB) * HGT) * (size_t)max_w + i;

    #pragma unroll
    for (int h = 0; h < HGT; ++h) {
        // y taps (block-uniform; identical rounding to R14/R15).
        const float yh  = __fadd_rn(__fmul_rn((float)h, each_h), top);
        const int   yfl = (int)floorf(yh);
        const int   ya  = min(max(yfl,     0), HIMG - 1);
        const int   yb  = min(max(yfl + 1, 0), HIMG - 1);
        const float wy1 = (float)yb - yh;
        const float wy0 = yh - (float)ya;

        const float wa  = wx1 * wy1;
        const float wb_ = wx1 * wy0;
        const float wc_ = wx0 * wy1;
        const float wd_ = wx0 * wy0;

        const float* r0p = base + (size_t)ya * WIMG;
        const float* r1p = base + (size_t)yb * WIMG;
        float* resph = resp0 + (size_t)h * max_w;

        #pragma unroll
        for (int c = 0; c < CPB; ++c) {
            const float* p0 = r0p + (size_t)c * (HIMG * WIMG);
            const float* p1 = r1p + (size_t)c * (HIMG * WIMG);
            const float v00 = p0[0];
            const float v01 = p0[1];
            const float v10 = p1[0];
            const float v11 = p1[1];
            // identical term order/grouping to R11-R15 (passed absmax):
            const float val = v00 * wa + v10 * wb_ + v01 * wc_ + v11 * wd_;
            __builtin_nontemporal_store(in_w ? val : 0.0f,
                                        resph + (size_t)c * (HGT * (size_t)max_w));
        }
    }
}

extern "C" void kernel_launch(void* const* d_in, const int* in_sizes, int n_in,
                              void* d_out, int out_size, void* d_ws, size_t ws_size,
                              hipStream_t stream) {
    const float* img   = (const float*)d_in[0];
    const float* boxes = (const float*)d_in[1];
    float* out = (float*)d_out;

    const int per_w = BIMG * JBOX * CCH * HGT + BIMG * JBOX;  // 131584
    const int max_w = out_size / per_w;

    float* res  = out;
    float* mask = out + (size_t)BIMG * JBOX * CCH * HGT * max_w;

    const int blocks = BIMG * JBOX * NCG;   // 2048 = 8 blocks/CU, no LDS
    roi_kernel<<<blocks, 256, 0, stream>>>(img, boxes, res, mask, max_w);
}